// Round 1
// baseline (3593.259 us; speedup 1.0000x reference)
//
#include <hip/hip_runtime.h>
#include <math.h>

#define DIM 2048
#define NHEAD 16
#define HDIM 128
#define SEQ 2048
#define BATCH 2

// ---------------- GEMM: C[M][N] = A[M][K] * B[N][K]^T (both row-major, K contiguous)
// 128x128 tile, BK=16, 256 threads, 8x8 register tile per thread.
#define BM 128
#define BN 128
#define BK 16
#define LDA_PAD (BM + 4)   // stride 132 floats
#define LDB_PAD (BN + 4)

__global__ __launch_bounds__(256) void gemm_nt(const float* __restrict__ A,
                                               const float* __restrict__ B,
                                               float* __restrict__ C,
                                               int M, int N, int K) {
    __shared__ float As[BK][LDA_PAD];
    __shared__ float Bs[BK][LDB_PAD];

    const int tid = threadIdx.x;
    const int ty = tid >> 4;      // 0..15
    const int tx = tid & 15;      // 0..15
    const int m0 = blockIdx.y * BM;
    const int n0 = blockIdx.x * BN;

    // staging indices: thread t loads row (t/2), k-offset (t%2)*8, 8 floats (2x float4)
    const int lr = tid >> 1;           // 0..127
    const int lk = (tid & 1) * 8;      // 0 or 8
    const float* Arow = A + (size_t)(m0 + lr) * K + lk;
    const float* Brow = B + (size_t)(n0 + lr) * K + lk;

    float acc[8][8];
#pragma unroll
    for (int i = 0; i < 8; ++i)
#pragma unroll
        for (int j = 0; j < 8; ++j) acc[i][j] = 0.f;

    for (int k0 = 0; k0 < K; k0 += BK) {
        float4 a0 = *(const float4*)(Arow + k0);
        float4 a1 = *(const float4*)(Arow + k0 + 4);
        float4 b0 = *(const float4*)(Brow + k0);
        float4 b1 = *(const float4*)(Brow + k0 + 4);
        __syncthreads();   // previous iteration's reads done before overwrite
        As[lk + 0][lr] = a0.x; As[lk + 1][lr] = a0.y;
        As[lk + 2][lr] = a0.z; As[lk + 3][lr] = a0.w;
        As[lk + 4][lr] = a1.x; As[lk + 5][lr] = a1.y;
        As[lk + 6][lr] = a1.z; As[lk + 7][lr] = a1.w;
        Bs[lk + 0][lr] = b0.x; Bs[lk + 1][lr] = b0.y;
        Bs[lk + 2][lr] = b0.z; Bs[lk + 3][lr] = b0.w;
        Bs[lk + 4][lr] = b1.x; Bs[lk + 5][lr] = b1.y;
        Bs[lk + 6][lr] = b1.z; Bs[lk + 7][lr] = b1.w;
        __syncthreads();

#pragma unroll
        for (int k = 0; k < BK; ++k) {
            float4 xa0 = *(const float4*)&As[k][ty * 4];
            float4 xa1 = *(const float4*)&As[k][64 + ty * 4];
            float4 xb0 = *(const float4*)&Bs[k][tx * 4];
            float4 xb1 = *(const float4*)&Bs[k][64 + tx * 4];
            float av[8] = {xa0.x, xa0.y, xa0.z, xa0.w, xa1.x, xa1.y, xa1.z, xa1.w};
            float bv[8] = {xb0.x, xb0.y, xb0.z, xb0.w, xb1.x, xb1.y, xb1.z, xb1.w};
#pragma unroll
            for (int i = 0; i < 8; ++i)
#pragma unroll
                for (int j = 0; j < 8; ++j) acc[i][j] += av[i] * bv[j];
        }
    }

    // epilogue: rows m0 + {ty*4+i, 64+ty*4+i}, cols n0 + {tx*4+j, 64+tx*4+j}
#pragma unroll
    for (int i = 0; i < 8; ++i) {
        int row = m0 + ((i < 4) ? (ty * 4 + i) : (64 + ty * 4 + (i - 4)));
        float* Crow = C + (size_t)row * N + n0;
        float4 c0 = make_float4(acc[i][0], acc[i][1], acc[i][2], acc[i][3]);
        float4 c1 = make_float4(acc[i][4], acc[i][5], acc[i][6], acc[i][7]);
        *(float4*)(Crow + tx * 4) = c0;
        *(float4*)(Crow + 64 + tx * 4) = c1;
    }
}

// ---------------- Flash-style causal attention, fp32.
// qkv layout: [b, n, 3, h, d] flattened: ((b*SEQ+n)*3*DIM) + sel*DIM + h*HDIM + d
// out layout: [b, n, h*HDIM + d]
#define QT 64
#define KT 64
#define LQ 132   // padded LDS row stride (floats)
#define LP 68

__global__ __launch_bounds__(256) void attn_fwd(const float* __restrict__ qkv,
                                                float* __restrict__ out) {
    __shared__ float Qs[QT][LQ];
    __shared__ float KVs[KT][LQ];
    __shared__ float Ps[QT][LP];

    const int qt = blockIdx.x;         // q tile
    const int bh = blockIdx.y;         // b*NHEAD + h
    const int b = bh >> 4, h = bh & 15;
    const int q0 = qt * QT;
    const int tid = threadIdx.x;
    const int ty = tid >> 4;   // 0..15 -> rows ty*4..+3
    const int tx = tid & 15;   // 0..15 -> S cols tx + 16*cc
    const float scale = 0.08838834764831845f;  // 1/sqrt(128)

    const size_t rowstride = 3 * DIM;
    const float* qbase = qkv + (size_t)(b * SEQ + q0) * rowstride + h * HDIM;
    const float* kbase = qkv + (size_t)(b * SEQ) * rowstride + DIM + h * HDIM;
    const float* vbase = kbase + DIM;

    // load Q tile (scaled)
    for (int i = tid; i < QT * (HDIM / 4); i += 256) {
        int r = i >> 5, c4 = (i & 31) * 4;
        float4 v = *(const float4*)(qbase + (size_t)r * rowstride + c4);
        Qs[r][c4 + 0] = v.x * scale; Qs[r][c4 + 1] = v.y * scale;
        Qs[r][c4 + 2] = v.z * scale; Qs[r][c4 + 3] = v.w * scale;
    }

    float m_r[4], l_r[4], acc[4][8];
#pragma unroll
    for (int r = 0; r < 4; ++r) {
        m_r[r] = -INFINITY; l_r[r] = 0.f;
#pragma unroll
        for (int j = 0; j < 8; ++j) acc[r][j] = 0.f;
    }

    for (int kt = 0; kt <= qt; ++kt) {
        const int k0 = kt * KT;
        __syncthreads();   // previous PV / Q-load done before KVs overwrite
        for (int i = tid; i < KT * (HDIM / 4); i += 256) {
            int r = i >> 5, c4 = (i & 31) * 4;
            float4 v = *(const float4*)(kbase + (size_t)(k0 + r) * rowstride + c4);
            KVs[r][c4 + 0] = v.x; KVs[r][c4 + 1] = v.y;
            KVs[r][c4 + 2] = v.z; KVs[r][c4 + 3] = v.w;
        }
        __syncthreads();

        // S = Q K^T  (rows ty*4+r, cols tx+16*cc)
        float s[4][4];
#pragma unroll
        for (int r = 0; r < 4; ++r)
#pragma unroll
            for (int c = 0; c < 4; ++c) s[r][c] = 0.f;

        for (int d0 = 0; d0 < HDIM; d0 += 4) {
            float4 q4[4], k4[4];
#pragma unroll
            for (int r = 0; r < 4; ++r) q4[r] = *(const float4*)&Qs[ty * 4 + r][d0];
#pragma unroll
            for (int c = 0; c < 4; ++c) k4[c] = *(const float4*)&KVs[tx + 16 * c][d0];
#pragma unroll
            for (int r = 0; r < 4; ++r)
#pragma unroll
                for (int c = 0; c < 4; ++c)
                    s[r][c] += q4[r].x * k4[c].x + q4[r].y * k4[c].y +
                               q4[r].z * k4[c].z + q4[r].w * k4[c].w;
        }

        if (kt == qt) {   // causal mask on diagonal tile
#pragma unroll
            for (int r = 0; r < 4; ++r)
#pragma unroll
                for (int c = 0; c < 4; ++c)
                    if (k0 + tx + 16 * c > q0 + ty * 4 + r) s[r][c] = -INFINITY;
        }

        // online softmax update + write P
#pragma unroll
        for (int r = 0; r < 4; ++r) {
            float mx = fmaxf(fmaxf(s[r][0], s[r][1]), fmaxf(s[r][2], s[r][3]));
            mx = fmaxf(mx, __shfl_xor(mx, 1));
            mx = fmaxf(mx, __shfl_xor(mx, 2));
            mx = fmaxf(mx, __shfl_xor(mx, 4));
            mx = fmaxf(mx, __shfl_xor(mx, 8));
            float mn = fmaxf(m_r[r], mx);
            float alpha = expf(m_r[r] - mn);   // exp(-inf)=0 on first tile
            m_r[r] = mn;
            float rs = 0.f;
#pragma unroll
            for (int c = 0; c < 4; ++c) {
                float p = expf(s[r][c] - mn);   // masked -> exp(-inf)=0
                Ps[ty * 4 + r][tx + 16 * c] = p;
                rs += p;
            }
            rs += __shfl_xor(rs, 1);
            rs += __shfl_xor(rs, 2);
            rs += __shfl_xor(rs, 4);
            rs += __shfl_xor(rs, 8);
            l_r[r] = l_r[r] * alpha + rs;
#pragma unroll
            for (int j = 0; j < 8; ++j) acc[r][j] *= alpha;
        }
        __syncthreads();   // S-phase reads of KVs done; Ps visible to all

        // load V tile into same buffer
        for (int i = tid; i < KT * (HDIM / 4); i += 256) {
            int r = i >> 5, c4 = (i & 31) * 4;
            float4 v = *(const float4*)(vbase + (size_t)(k0 + r) * rowstride + c4);
            KVs[r][c4 + 0] = v.x; KVs[r][c4 + 1] = v.y;
            KVs[r][c4 + 2] = v.z; KVs[r][c4 + 3] = v.w;
        }
        __syncthreads();

        // acc += P @ V   (out cols tx*4..+3 and 64+tx*4..+3)
        for (int kk0 = 0; kk0 < KT; kk0 += 4) {
            float4 p4[4];
#pragma unroll
            for (int r = 0; r < 4; ++r) p4[r] = *(const float4*)&Ps[ty * 4 + r][kk0];
#pragma unroll
            for (int kk = 0; kk < 4; ++kk) {
                float4 v0 = *(const float4*)&KVs[kk0 + kk][tx * 4];
                float4 v1 = *(const float4*)&KVs[kk0 + kk][64 + tx * 4];
#pragma unroll
                for (int r = 0; r < 4; ++r) {
                    float p = (kk == 0) ? p4[r].x : (kk == 1) ? p4[r].y
                              : (kk == 2) ? p4[r].z : p4[r].w;
                    acc[r][0] += p * v0.x; acc[r][1] += p * v0.y;
                    acc[r][2] += p * v0.z; acc[r][3] += p * v0.w;
                    acc[r][4] += p * v1.x; acc[r][5] += p * v1.y;
                    acc[r][6] += p * v1.z; acc[r][7] += p * v1.w;
                }
            }
        }
    }

    // epilogue: out[b, q, h*128 + d] = acc / l
#pragma unroll
    for (int r = 0; r < 4; ++r) {
        float inv = 1.f / l_r[r];
        int row = q0 + ty * 4 + r;
        float* optr = out + (size_t)(b * SEQ + row) * DIM + h * HDIM;
        float4 c0 = make_float4(acc[r][0] * inv, acc[r][1] * inv,
                                acc[r][2] * inv, acc[r][3] * inv);
        float4 c1 = make_float4(acc[r][4] * inv, acc[r][5] * inv,
                                acc[r][6] * inv, acc[r][7] * inv);
        *(float4*)(optr + tx * 4) = c0;
        *(float4*)(optr + 64 + tx * 4) = c1;
    }
}

extern "C" void kernel_launch(void* const* d_in, const int* in_sizes, int n_in,
                              void* d_out, int out_size, void* d_ws, size_t ws_size,
                              hipStream_t stream) {
    const float* x     = (const float*)d_in[0];   // [2,2048,2048]
    const float* w_qkv = (const float*)d_in[1];   // [6144,2048]
    const float* w_out = (const float*)d_in[2];   // [2048,2048]
    float* out = (float*)d_out;                   // [2,2048,2048]

    float* qkv     = (float*)d_ws;                           // 4096*6144 floats (100.7 MB)
    float* attn_ws = qkv + (size_t)BATCH * SEQ * 3 * DIM;    // 4096*2048 floats (33.5 MB)

    const int Mrows = BATCH * SEQ;   // 4096

    // 1) qkv = x @ w_qkv^T   [4096, 6144]
    gemm_nt<<<dim3(3 * DIM / BN, Mrows / BM), 256, 0, stream>>>(
        x, w_qkv, qkv, Mrows, 3 * DIM, DIM);

    // 2) causal flash attention -> attn_ws [4096, 2048] ([b,n,h*d])
    attn_fwd<<<dim3(SEQ / QT, BATCH * NHEAD), 256, 0, stream>>>(qkv, attn_ws);

    // 3) out = attn_ws @ w_out^T  [4096, 2048]
    gemm_nt<<<dim3(DIM / BN, Mrows / BM), 256, 0, stream>>>(
        attn_ws, w_out, out, Mrows, DIM, DIM);
}

// Round 3
// 1888.600 us; speedup vs baseline: 1.9026x; 1.9026x over previous
//
#include <hip/hip_runtime.h>
#include <math.h>

#define DIM 2048
#define NHEAD 16
#define HDIM 128
#define SEQ 2048
#define BATCH 2

typedef __attribute__((ext_vector_type(8))) short bf16x8;
typedef __attribute__((ext_vector_type(4))) float f32x4;

// RNE round fp32 -> bf16 (returned in low 16 bits), pure integer.
__device__ __forceinline__ unsigned f32_to_bf16_rne(float f) {
    unsigned u = __builtin_bit_cast(unsigned, f);
    return (u + 0x7fffu + ((u >> 16) & 1u)) >> 16;
}

// Split fp32 pair -> packed bf16 hi (truncation) + packed bf16 lo (RNE of residual).
// f == hi_f + lo_f to ~2^-17 relative.
__device__ __forceinline__ void split2(float f0, float f1, unsigned& hi2, unsigned& lo2) {
    unsigned u0 = __builtin_bit_cast(unsigned, f0);
    unsigned u1 = __builtin_bit_cast(unsigned, f1);
    hi2 = __builtin_amdgcn_perm(u1, u0, 0x07060302u);   // [u1.hi16 : u0.hi16] -> lanes (f0 low half)
    float h0 = __builtin_bit_cast(float, u0 & 0xffff0000u);
    float h1 = __builtin_bit_cast(float, u1 & 0xffff0000u);
    lo2 = f32_to_bf16_rne(f0 - h0) | (f32_to_bf16_rne(f1 - h1) << 16);
}

// ---------------- split-bf16 3-pass MFMA GEMM: C[M][N] = A[M][K] x B[N][K]^T
// fp32 in HBM; staged to LDS as bf16 hi/lo (convert-on-stage). 128x128 tile, BK=32.
// 4 waves, each owns a 64x64 quadrant = 4x4 frags of 16x16x32 MFMA. Passes: hh, hl, lh.
#define GBK 32

__global__ __launch_bounds__(256) void gemm_nt_split(
    const float* __restrict__ A, const float* __restrict__ B, float* __restrict__ C,
    int M, int N, int K) {
    __shared__ unsigned short As[2][128][GBK];   // [hi/lo][row][k] bf16, 16KB
    __shared__ unsigned short Bs[2][128][GBK];   // 16KB

    const int tid = threadIdx.x;

    // XCD-aware bijective swizzle (nwg % 8 == 0 for all our launches)
    const int nbx = gridDim.x;
    const int nwg = nbx * gridDim.y;
    const int flat = blockIdx.y * nbx + blockIdx.x;
    const int per = nwg >> 3;
    const int swz = (flat & 7) * per + (flat >> 3);
    const int m0 = (swz / nbx) * 128;
    const int n0 = (swz % nbx) * 128;

    const int lane = tid & 63;
    const int wave = tid >> 6;
    const int wm = (wave >> 1) * 64;
    const int wn = (wave & 1) * 64;
    const int lr = lane & 15;
    const int lk = (lane >> 4) * 8;      // ushort offset within 32-wide K row

    const int srow = tid >> 1;           // 0..127 (tile row staged by this thread)
    const int scol = (tid & 1) * 16;     // first of 16 contiguous k-elems
    const float* Ap = A + (size_t)(m0 + srow) * K + scol;
    const float* Bp = B + (size_t)(n0 + srow) * K + scol;

    f32x4 acc[4][4];
#pragma unroll
    for (int i = 0; i < 4; ++i)
#pragma unroll
        for (int j = 0; j < 4; ++j) acc[i][j] = f32x4{0.f, 0.f, 0.f, 0.f};

    for (int k0 = 0; k0 < K; k0 += GBK) {
        float4 av[4], bv[4];
#pragma unroll
        for (int i = 0; i < 4; ++i) {
            av[i] = *(const float4*)(Ap + k0 + 4 * i);
            bv[i] = *(const float4*)(Bp + k0 + 4 * i);
        }
        __syncthreads();   // prior iteration's fragment reads complete

        unsigned ah[8], al[8], bh[8], bl[8];
#pragma unroll
        for (int i = 0; i < 4; ++i) {
            split2(av[i].x, av[i].y, ah[2 * i], al[2 * i]);
            split2(av[i].z, av[i].w, ah[2 * i + 1], al[2 * i + 1]);
            split2(bv[i].x, bv[i].y, bh[2 * i], bl[2 * i]);
            split2(bv[i].z, bv[i].w, bh[2 * i + 1], bl[2 * i + 1]);
        }

        *(uint4*)&As[0][srow][scol]     = make_uint4(ah[0], ah[1], ah[2], ah[3]);
        *(uint4*)&As[0][srow][scol + 8] = make_uint4(ah[4], ah[5], ah[6], ah[7]);
        *(uint4*)&As[1][srow][scol]     = make_uint4(al[0], al[1], al[2], al[3]);
        *(uint4*)&As[1][srow][scol + 8] = make_uint4(al[4], al[5], al[6], al[7]);
        *(uint4*)&Bs[0][srow][scol]     = make_uint4(bh[0], bh[1], bh[2], bh[3]);
        *(uint4*)&Bs[0][srow][scol + 8] = make_uint4(bh[4], bh[5], bh[6], bh[7]);
        *(uint4*)&Bs[1][srow][scol]     = make_uint4(bl[0], bl[1], bl[2], bl[3]);
        *(uint4*)&Bs[1][srow][scol + 8] = make_uint4(bl[4], bl[5], bl[6], bl[7]);
        __syncthreads();

        bf16x8 a0[4], a1[4], b0[4], b1[4];
#pragma unroll
        for (int i = 0; i < 4; ++i) {
            a0[i] = *(const bf16x8*)&As[0][wm + i * 16 + lr][lk];
            a1[i] = *(const bf16x8*)&As[1][wm + i * 16 + lr][lk];
            b0[i] = *(const bf16x8*)&Bs[0][wn + i * 16 + lr][lk];
            b1[i] = *(const bf16x8*)&Bs[1][wn + i * 16 + lr][lk];
        }
        // pass 1: Ah*Bh ; pass 2: Ah*Bl ; pass 3: Al*Bh
#pragma unroll
        for (int mi = 0; mi < 4; ++mi)
#pragma unroll
            for (int ni = 0; ni < 4; ++ni)
                acc[mi][ni] = __builtin_amdgcn_mfma_f32_16x16x32_bf16(a0[mi], b0[ni], acc[mi][ni], 0, 0, 0);
#pragma unroll
        for (int mi = 0; mi < 4; ++mi)
#pragma unroll
            for (int ni = 0; ni < 4; ++ni)
                acc[mi][ni] = __builtin_amdgcn_mfma_f32_16x16x32_bf16(a0[mi], b1[ni], acc[mi][ni], 0, 0, 0);
#pragma unroll
        for (int mi = 0; mi < 4; ++mi)
#pragma unroll
            for (int ni = 0; ni < 4; ++ni)
                acc[mi][ni] = __builtin_amdgcn_mfma_f32_16x16x32_bf16(a1[mi], b0[ni], acc[mi][ni], 0, 0, 0);
    }

    // epilogue: C/D map (m89-verified): col = lane&15, row = (lane>>4)*4 + reg
    const int crow = (lane >> 4) * 4;
    const int ccol = lane & 15;
#pragma unroll
    for (int mi = 0; mi < 4; ++mi)
#pragma unroll
        for (int ni = 0; ni < 4; ++ni) {
            size_t base = (size_t)(m0 + wm + mi * 16 + crow) * N + (n0 + wn + ni * 16 + ccol);
            C[base]         = acc[mi][ni][0];
            C[base + N]     = acc[mi][ni][1];
            C[base + 2 * N] = acc[mi][ni][2];
            C[base + 3 * N] = acc[mi][ni][3];
        }
}

// ---------------- Flash-style causal attention, fp32 vector.
// QT=32: LDS 59.4KB -> 2 blocks/CU (8 waves/CU), grid 2048 blocks.
#define QT 32
#define KT 64
#define LQ 132   // padded fp32 row stride
#define LP 68

__global__ __launch_bounds__(256) void attn_fwd(const float* __restrict__ qkv,
                                                float* __restrict__ out) {
    __shared__ float Qs[QT][LQ];    // 16.9KB
    __shared__ float KVs[KT][LQ];   // 33.8KB (K then V, time-shared)
    __shared__ float Ps[QT][LP];    // 8.7KB

    const int qt = blockIdx.x;
    const int bh = blockIdx.y;
    const int b = bh >> 4, h = bh & 15;
    const int q0 = qt * QT;
    const int tid = threadIdx.x;
    const int ty = tid >> 4;   // 0..15 -> rows ty*2 + {0,1}
    const int tx = tid & 15;   // S-cols tx + 16*c
    const float scale = 0.08838834764831845f;  // 1/sqrt(128)

    const size_t rowstride = 3 * DIM;
    const float* qbase = qkv + (size_t)(b * SEQ + q0) * rowstride + h * HDIM;
    const float* kbase = qkv + (size_t)(b * SEQ) * rowstride + DIM + h * HDIM;
    const float* vbase = kbase + DIM;

    for (int i = tid; i < QT * 32; i += 256) {   // 32 float4 per row
        int r = i >> 5, c4 = (i & 31) * 4;
        float4 v = *(const float4*)(qbase + (size_t)r * rowstride + c4);
        Qs[r][c4 + 0] = v.x * scale; Qs[r][c4 + 1] = v.y * scale;
        Qs[r][c4 + 2] = v.z * scale; Qs[r][c4 + 3] = v.w * scale;
    }

    float m_r[2] = {-INFINITY, -INFINITY};
    float l_r[2] = {0.f, 0.f};
    float acc[2][8];
#pragma unroll
    for (int r = 0; r < 2; ++r)
#pragma unroll
        for (int j = 0; j < 8; ++j) acc[r][j] = 0.f;

    const int nkt = (q0 + QT + KT - 1) / KT;
    for (int kt = 0; kt < nkt; ++kt) {
        const int k0 = kt * KT;
        __syncthreads();   // prior PV reads (and Q-load on iter 0) ordering
        for (int i = tid; i < KT * 32; i += 256) {
            int r = i >> 5, c4 = (i & 31) * 4;
            *(float4*)&KVs[r][c4] = *(const float4*)(kbase + (size_t)(k0 + r) * rowstride + c4);
        }
        __syncthreads();

        float s[2][4];
#pragma unroll
        for (int r = 0; r < 2; ++r)
#pragma unroll
            for (int c = 0; c < 4; ++c) s[r][c] = 0.f;

        for (int d0 = 0; d0 < HDIM; d0 += 4) {
            float4 q4[2], k4[4];
            q4[0] = *(const float4*)&Qs[ty * 2 + 0][d0];
            q4[1] = *(const float4*)&Qs[ty * 2 + 1][d0];
#pragma unroll
            for (int c = 0; c < 4; ++c) k4[c] = *(const float4*)&KVs[tx + 16 * c][d0];
#pragma unroll
            for (int r = 0; r < 2; ++r)
#pragma unroll
                for (int c = 0; c < 4; ++c)
                    s[r][c] += q4[r].x * k4[c].x + q4[r].y * k4[c].y +
                               q4[r].z * k4[c].z + q4[r].w * k4[c].w;
        }

        if (kt == nkt - 1) {   // causal mask (only last tile crosses the diagonal)
#pragma unroll
            for (int r = 0; r < 2; ++r)
#pragma unroll
                for (int c = 0; c < 4; ++c)
                    if (k0 + tx + 16 * c > q0 + ty * 2 + r) s[r][c] = -INFINITY;
        }

#pragma unroll
        for (int r = 0; r < 2; ++r) {
            float mx = fmaxf(fmaxf(s[r][0], s[r][1]), fmaxf(s[r][2], s[r][3]));
            mx = fmaxf(mx, __shfl_xor(mx, 1));
            mx = fmaxf(mx, __shfl_xor(mx, 2));
            mx = fmaxf(mx, __shfl_xor(mx, 4));
            mx = fmaxf(mx, __shfl_xor(mx, 8));
            float mn = fmaxf(m_r[r], mx);
            float alpha = expf(m_r[r] - mn);
            m_r[r] = mn;
            float rs = 0.f;
#pragma unroll
            for (int c = 0; c < 4; ++c) {
                float p = expf(s[r][c] - mn);
                Ps[ty * 2 + r][tx + 16 * c] = p;
                rs += p;
            }
            rs += __shfl_xor(rs, 1);
            rs += __shfl_xor(rs, 2);
            rs += __shfl_xor(rs, 4);
            rs += __shfl_xor(rs, 8);
            l_r[r] = l_r[r] * alpha + rs;
#pragma unroll
            for (int j = 0; j < 8; ++j) acc[r][j] *= alpha;
        }
        __syncthreads();   // K reads done + Ps visible

        for (int i = tid; i < KT * 32; i += 256) {
            int r = i >> 5, c4 = (i & 31) * 4;
            *(float4*)&KVs[r][c4] = *(const float4*)(vbase + (size_t)(k0 + r) * rowstride + c4);
        }
        __syncthreads();

        for (int kk0 = 0; kk0 < KT; kk0 += 4) {
            float4 p4[2];
            p4[0] = *(const float4*)&Ps[ty * 2 + 0][kk0];
            p4[1] = *(const float4*)&Ps[ty * 2 + 1][kk0];
#pragma unroll
            for (int kk = 0; kk < 4; ++kk) {
                float4 v0 = *(const float4*)&KVs[kk0 + kk][tx * 4];
                float4 v1 = *(const float4*)&KVs[kk0 + kk][64 + tx * 4];
#pragma unroll
                for (int r = 0; r < 2; ++r) {
                    float p = (kk == 0) ? p4[r].x : (kk == 1) ? p4[r].y
                              : (kk == 2) ? p4[r].z : p4[r].w;
                    acc[r][0] += p * v0.x; acc[r][1] += p * v0.y;
                    acc[r][2] += p * v0.z; acc[r][3] += p * v0.w;
                    acc[r][4] += p * v1.x; acc[r][5] += p * v1.y;
                    acc[r][6] += p * v1.z; acc[r][7] += p * v1.w;
                }
            }
        }
    }

#pragma unroll
    for (int r = 0; r < 2; ++r) {
        float inv = 1.f / l_r[r];
        int row = q0 + ty * 2 + r;
        float* optr = out + (size_t)(b * SEQ + row) * DIM + h * HDIM;
        float4 c0 = make_float4(acc[r][0] * inv, acc[r][1] * inv, acc[r][2] * inv, acc[r][3] * inv);
        float4 c1 = make_float4(acc[r][4] * inv, acc[r][5] * inv, acc[r][6] * inv, acc[r][7] * inv);
        *(float4*)(optr + tx * 4) = c0;
        *(float4*)(optr + 64 + tx * 4) = c1;
    }
}

extern "C" void kernel_launch(void* const* d_in, const int* in_sizes, int n_in,
                              void* d_out, int out_size, void* d_ws, size_t ws_size,
                              hipStream_t stream) {
    const float* x     = (const float*)d_in[0];   // [2,2048,2048]
    const float* w_qkv = (const float*)d_in[1];   // [6144,2048]
    const float* w_out = (const float*)d_in[2];   // [2048,2048]
    float* out = (float*)d_out;                   // [2,2048,2048]

    float* qkv     = (float*)d_ws;                           // 100.7 MB
    float* attn_ws = qkv + (size_t)BATCH * SEQ * 3 * DIM;    // 33.5 MB

    const int Mrows = BATCH * SEQ;   // 4096

    // 1) qkv = x @ w_qkv^T   [4096, 6144]  (split-bf16 MFMA)
    gemm_nt_split<<<dim3(3 * DIM / 128, Mrows / 128), 256, 0, stream>>>(
        x, w_qkv, qkv, Mrows, 3 * DIM, DIM);

    // 2) causal flash attention -> attn_ws [4096, 2048]
    attn_fwd<<<dim3(SEQ / QT, BATCH * NHEAD), 256, 0, stream>>>(qkv, attn_ws);

    // 3) out = attn_ws @ w_out^T  [4096, 2048]  (split-bf16 MFMA)
    gemm_nt_split<<<dim3(DIM / 128, Mrows / 128), 256, 0, stream>>>(
        attn_ws, w_out, out, Mrows, DIM, DIM);
}

// Round 7
// 1169.212 us; speedup vs baseline: 3.0732x; 1.6153x over previous
//
#include <hip/hip_runtime.h>
#include <math.h>

#define DIM 2048
#define NHEAD 16
#define HDIM 128
#define SEQ 2048
#define BATCH 2

typedef __attribute__((ext_vector_type(8))) short bf16x8;
typedef __attribute__((ext_vector_type(4))) float f32x4;

// RNE round fp32 -> bf16 (low 16 bits), pure integer.
__device__ __forceinline__ unsigned f32_to_bf16_rne(float f) {
    unsigned u = __builtin_bit_cast(unsigned, f);
    return (u + 0x7fffu + ((u >> 16) & 1u)) >> 16;
}

// Split fp32 pair -> packed bf16 hi (truncation) + packed bf16 lo (RNE of residual).
__device__ __forceinline__ void split2(float f0, float f1, unsigned& hi2, unsigned& lo2) {
    unsigned u0 = __builtin_bit_cast(unsigned, f0);
    unsigned u1 = __builtin_bit_cast(unsigned, f1);
    hi2 = __builtin_amdgcn_perm(u1, u0, 0x07060302u);   // [u1.hi16 : u0.hi16]
    float h0 = __builtin_bit_cast(float, u0 & 0xffff0000u);
    float h1 = __builtin_bit_cast(float, u1 & 0xffff0000u);
    lo2 = f32_to_bf16_rne(f0 - h0) | (f32_to_bf16_rne(f1 - h1) << 16);
}

// ---------------- split-bf16 3-pass MFMA GEMM (verified R3) ----------------
#define GBK 32

__global__ __launch_bounds__(256) void gemm_nt_split(
    const float* __restrict__ A, const float* __restrict__ B, float* __restrict__ C,
    int M, int N, int K) {
    __shared__ unsigned short As[2][128][GBK];
    __shared__ unsigned short Bs[2][128][GBK];

    const int tid = threadIdx.x;

    const int nbx = gridDim.x;
    const int nwg = nbx * gridDim.y;
    const int flat = blockIdx.y * nbx + blockIdx.x;
    const int per = nwg >> 3;
    const int swz = (flat & 7) * per + (flat >> 3);
    const int m0 = (swz / nbx) * 128;
    const int n0 = (swz % nbx) * 128;

    const int lane = tid & 63;
    const int wave = tid >> 6;
    const int wm = (wave >> 1) * 64;
    const int wn = (wave & 1) * 64;
    const int lr = lane & 15;
    const int lk = (lane >> 4) * 8;

    const int srow = tid >> 1;
    const int scol = (tid & 1) * 16;
    const float* Ap = A + (size_t)(m0 + srow) * K + scol;
    const float* Bp = B + (size_t)(n0 + srow) * K + scol;

    f32x4 acc[4][4];
#pragma unroll
    for (int i = 0; i < 4; ++i)
#pragma unroll
        for (int j = 0; j < 4; ++j) acc[i][j] = f32x4{0.f, 0.f, 0.f, 0.f};

    for (int k0 = 0; k0 < K; k0 += GBK) {
        float4 av[4], bv[4];
#pragma unroll
        for (int i = 0; i < 4; ++i) {
            av[i] = *(const float4*)(Ap + k0 + 4 * i);
            bv[i] = *(const float4*)(Bp + k0 + 4 * i);
        }
        __syncthreads();

        unsigned ah[8], al[8], bh[8], bl[8];
#pragma unroll
        for (int i = 0; i < 4; ++i) {
            split2(av[i].x, av[i].y, ah[2 * i], al[2 * i]);
            split2(av[i].z, av[i].w, ah[2 * i + 1], al[2 * i + 1]);
            split2(bv[i].x, bv[i].y, bh[2 * i], bl[2 * i]);
            split2(bv[i].z, bv[i].w, bh[2 * i + 1], bl[2 * i + 1]);
        }

        *(uint4*)&As[0][srow][scol]     = make_uint4(ah[0], ah[1], ah[2], ah[3]);
        *(uint4*)&As[0][srow][scol + 8] = make_uint4(ah[4], ah[5], ah[6], ah[7]);
        *(uint4*)&As[1][srow][scol]     = make_uint4(al[0], al[1], al[2], al[3]);
        *(uint4*)&As[1][srow][scol + 8] = make_uint4(al[4], al[5], al[6], al[7]);
        *(uint4*)&Bs[0][srow][scol]     = make_uint4(bh[0], bh[1], bh[2], bh[3]);
        *(uint4*)&Bs[0][srow][scol + 8] = make_uint4(bh[4], bh[5], bh[6], bh[7]);
        *(uint4*)&Bs[1][srow][scol]     = make_uint4(bl[0], bl[1], bl[2], bl[3]);
        *(uint4*)&Bs[1][srow][scol + 8] = make_uint4(bl[4], bl[5], bl[6], bl[7]);
        __syncthreads();

        bf16x8 a0[4], a1[4], b0[4], b1[4];
#pragma unroll
        for (int i = 0; i < 4; ++i) {
            a0[i] = *(const bf16x8*)&As[0][wm + i * 16 + lr][lk];
            a1[i] = *(const bf16x8*)&As[1][wm + i * 16 + lr][lk];
            b0[i] = *(const bf16x8*)&Bs[0][wn + i * 16 + lr][lk];
            b1[i] = *(const bf16x8*)&Bs[1][wn + i * 16 + lr][lk];
        }
#pragma unroll
        for (int mi = 0; mi < 4; ++mi)
#pragma unroll
            for (int ni = 0; ni < 4; ++ni)
                acc[mi][ni] = __builtin_amdgcn_mfma_f32_16x16x32_bf16(a0[mi], b0[ni], acc[mi][ni], 0, 0, 0);
#pragma unroll
        for (int mi = 0; mi < 4; ++mi)
#pragma unroll
            for (int ni = 0; ni < 4; ++ni)
                acc[mi][ni] = __builtin_amdgcn_mfma_f32_16x16x32_bf16(a0[mi], b1[ni], acc[mi][ni], 0, 0, 0);
#pragma unroll
        for (int mi = 0; mi < 4; ++mi)
#pragma unroll
            for (int ni = 0; ni < 4; ++ni)
                acc[mi][ni] = __builtin_amdgcn_mfma_f32_16x16x32_bf16(a1[mi], b0[ni], acc[mi][ni], 0, 0, 0);
    }

    const int crow = (lane >> 4) * 4;
    const int ccol = lane & 15;
#pragma unroll
    for (int mi = 0; mi < 4; ++mi)
#pragma unroll
        for (int ni = 0; ni < 4; ++ni) {
            size_t base = (size_t)(m0 + wm + mi * 16 + crow) * N + (n0 + wn + ni * 16 + ccol);
            C[base]         = acc[mi][ni][0];
            C[base + N]     = acc[mi][ni][1];
            C[base + 2 * N] = acc[mi][ni][2];
            C[base + 3 * N] = acc[mi][ni][3];
        }
}

// ---------------- MFMA flash attention, split-bf16 (3-pass QK^T, 3-pass PV).
// QB=64 q-rows/block, 4 waves x 16 rows. K and V^T time-share one LDS buffer.
// All LDS tiles XOR-chunk swizzled: 16B chunk index ^= (row & 7)  -> <=2-way conflicts.
#define QB 64

__global__ __launch_bounds__(256) void attn_mfma(const float* __restrict__ qkv,
                                                 float* __restrict__ out) {
    __shared__ unsigned short QsH[QB * 128], QsL[QB * 128];   // [row][d] 256B rows, 32KB
    __shared__ unsigned short KVH[8192], KVL[8192];           // K:[64][128] / Vt:[128][64], 32KB
    __shared__ unsigned short PsH[QB * 64], PsL[QB * 64];     // [row][k] 128B rows, 16KB

    const int qt = blockIdx.x;
    const int bh = blockIdx.y;
    const int b = bh >> 4, h = bh & 15;
    const int q0 = qt * QB;
    const int tid = threadIdx.x;
    const int lane = tid & 63;
    const int wave = tid >> 6;
    const int lr = lane & 15;       // fragment row/col lane index
    const int lg = lane >> 4;       // fragment k-group
    const int wq = wave * 16;       // this wave's q-row base within tile
    const float scale = 0.08838834764831845f;  // 1/sqrt(128)

    const size_t rs = 3 * DIM;      // qkv row stride (floats)
    const float* qsrc = qkv + (size_t)(b * SEQ + q0) * rs + h * HDIM;
    const float* ksrc = qkv + (size_t)(b * SEQ) * rs + DIM + h * HDIM;
    const float* vsrc = ksrc + DIM;

    // ---- stage Q (scaled, split hi/lo). 64 rows x 32 float4 = 2048 tasks.
#pragma unroll
    for (int i = 0; i < 8; ++i) {
        int idx = tid + 256 * i;
        int row = idx >> 5, c = idx & 31;          // float4 at d = 4c
        float4 v = *(const float4*)(qsrc + (size_t)row * rs + 4 * c);
        unsigned h0, l0, h1, l1;
        split2(v.x * scale, v.y * scale, h0, l0);
        split2(v.z * scale, v.w * scale, h1, l1);
        int k = 4 * c;
        int off = row * 128 + (((k >> 3) ^ (row & 7)) << 3) + (k & 7);
        *(uint2*)&QsH[off] = make_uint2(h0, h1);
        *(uint2*)&QsL[off] = make_uint2(l0, l1);
    }

    float m_r[4], l_r[4];
    f32x4 oc[8];
#pragma unroll
    for (int r = 0; r < 4; ++r) { m_r[r] = -INFINITY; l_r[r] = 0.f; }
#pragma unroll
    for (int d = 0; d < 8; ++d) oc[d] = f32x4{0.f, 0.f, 0.f, 0.f};

    const int nkt = qt + 1;   // KT == QB == 64
    for (int kt = 0; kt < nkt; ++kt) {
        const int k0 = kt * QB;
        __syncthreads();   // prior PV reads of KV done (and Q staged, iter 0)

        // ---- stage K tile [64][128] hi/lo
#pragma unroll
        for (int i = 0; i < 8; ++i) {
            int idx = tid + 256 * i;
            int row = idx >> 5, c = idx & 31;
            float4 v = *(const float4*)(ksrc + (size_t)(k0 + row) * rs + 4 * c);
            unsigned h0, l0, h1, l1;
            split2(v.x, v.y, h0, l0);
            split2(v.z, v.w, h1, l1);
            int k = 4 * c;
            int off = row * 128 + (((k >> 3) ^ (row & 7)) << 3) + (k & 7);
            *(uint2*)&KVH[off] = make_uint2(h0, h1);
            *(uint2*)&KVL[off] = make_uint2(l0, l1);
        }
        __syncthreads();

        // ---- S = Q K^T : wave computes 16 rows x 64 cols = 4 frags, 3 passes
        f32x4 sc[4];
#pragma unroll
        for (int kb = 0; kb < 4; ++kb) sc[kb] = f32x4{0.f, 0.f, 0.f, 0.f};

#pragma unroll
        for (int ks = 0; ks < 4; ++ks) {           // d = ks*32 .. +31
            const int arow = wq + lr;
            const int aoff = arow * 128 + ((((ks << 2) + lg) ^ (arow & 7)) << 3);
            bf16x8 aH = *(const bf16x8*)&QsH[aoff];
            bf16x8 aL = *(const bf16x8*)&QsL[aoff];
            bf16x8 bH[4], bL[4];
#pragma unroll
            for (int kb = 0; kb < 4; ++kb) {
                const int brow = kb * 16 + lr;
                const int boff = brow * 128 + ((((ks << 2) + lg) ^ (brow & 7)) << 3);
                bH[kb] = *(const bf16x8*)&KVH[boff];
                bL[kb] = *(const bf16x8*)&KVL[boff];
            }
#pragma unroll
            for (int kb = 0; kb < 4; ++kb)
                sc[kb] = __builtin_amdgcn_mfma_f32_16x16x32_bf16(aH, bH[kb], sc[kb], 0, 0, 0);
#pragma unroll
            for (int kb = 0; kb < 4; ++kb)
                sc[kb] = __builtin_amdgcn_mfma_f32_16x16x32_bf16(aH, bL[kb], sc[kb], 0, 0, 0);
#pragma unroll
            for (int kb = 0; kb < 4; ++kb)
                sc[kb] = __builtin_amdgcn_mfma_f32_16x16x32_bf16(aL, bH[kb], sc[kb], 0, 0, 0);
        }

        // ---- causal mask (last tile only)
        if (kt == nkt - 1) {
#pragma unroll
            for (int kb = 0; kb < 4; ++kb)
#pragma unroll
                for (int r = 0; r < 4; ++r)
                    if (k0 + kb * 16 + lr > q0 + wq + lg * 4 + r) sc[kb][r] = -INFINITY;
        }

        // ---- online softmax (C-layout: lane holds rows lg*4+r, cols kb*16+lr)
#pragma unroll
        for (int r = 0; r < 4; ++r) {
            float mx = fmaxf(fmaxf(sc[0][r], sc[1][r]), fmaxf(sc[2][r], sc[3][r]));
            mx = fmaxf(mx, __shfl_xor(mx, 1));
            mx = fmaxf(mx, __shfl_xor(mx, 2));
            mx = fmaxf(mx, __shfl_xor(mx, 4));
            mx = fmaxf(mx, __shfl_xor(mx, 8));
            float mn = fmaxf(m_r[r], mx);
            float alpha = __expf(m_r[r] - mn);
            m_r[r] = mn;
            const int prow = wq + lg * 4 + r;
            float rsum = 0.f;
#pragma unroll
            for (int kb = 0; kb < 4; ++kb) {
                float p = __expf(sc[kb][r] - mn);
                rsum += p;
                unsigned u = __builtin_bit_cast(unsigned, p);
                unsigned ph = u >> 16;                                   // trunc bf16
                float pl = p - __builtin_bit_cast(float, u & 0xffff0000u);
                const int col = kb * 16 + lr;
                const int poff = prow * 64 + (((col >> 3) ^ (prow & 7)) << 3) + (col & 7);
                PsH[poff] = (unsigned short)ph;
                PsL[poff] = (unsigned short)f32_to_bf16_rne(pl);
            }
            rsum += __shfl_xor(rsum, 1);
            rsum += __shfl_xor(rsum, 2);
            rsum += __shfl_xor(rsum, 4);
            rsum += __shfl_xor(rsum, 8);
            l_r[r] = l_r[r] * alpha + rsum;
#pragma unroll
            for (int d = 0; d < 8; ++d) oc[d][r] *= alpha;
        }
        __syncthreads();   // all waves done reading K before V overwrites

        // ---- stage V^T [128 d][64 k] hi/lo (k-major scalar loads, coalesced in d)
#pragma unroll
        for (int i = 0; i < 4; ++i) {
            int task = tid + 256 * i;
            int d = task & 127, kg = task >> 7;    // kg: 8-k group
            float v[8];
#pragma unroll
            for (int j = 0; j < 8; ++j)
                v[j] = vsrc[(size_t)(k0 + kg * 8 + j) * rs + d];
            unsigned h0, l0, h1, l1, h2, l2, h3, l3;
            split2(v[0], v[1], h0, l0);
            split2(v[2], v[3], h1, l1);
            split2(v[4], v[5], h2, l2);
            split2(v[6], v[7], h3, l3);
            int off = d * 64 + ((kg ^ (d & 7)) << 3);
            *(uint4*)&KVH[off] = make_uint4(h0, h1, h2, h3);
            *(uint4*)&KVL[off] = make_uint4(l0, l1, l2, l3);
        }
        __syncthreads();

        // ---- O += P V : 8 d-frags x 2 ksteps x 3 passes
#pragma unroll
        for (int ks = 0; ks < 2; ++ks) {
            const int arow = wq + lr;
            const int kk = (ks << 2) + lg;   // chunk = k>>3, k = ks*32 + lg*8  [R4 FIX: was (ks<<1)+lg]
            const int aoff = arow * 64 + ((kk ^ (arow & 7)) << 3);
            bf16x8 aH = *(const bf16x8*)&PsH[aoff];
            bf16x8 aL = *(const bf16x8*)&PsL[aoff];
#pragma unroll
            for (int db = 0; db < 8; ++db) {
                const int drow = db * 16 + lr;
                const int boff = drow * 64 + ((kk ^ (drow & 7)) << 3);
                bf16x8 bH = *(const bf16x8*)&KVH[boff];
                bf16x8 bL = *(const bf16x8*)&KVL[boff];
                oc[db] = __builtin_amdgcn_mfma_f32_16x16x32_bf16(aH, bH, oc[db], 0, 0, 0);
                oc[db] = __builtin_amdgcn_mfma_f32_16x16x32_bf16(aL, bH, oc[db], 0, 0, 0);
                oc[db] = __builtin_amdgcn_mfma_f32_16x16x32_bf16(aH, bL, oc[db], 0, 0, 0);
            }
        }
    }

    // ---- epilogue
#pragma unroll
    for (int r = 0; r < 4; ++r) {
        float inv = 1.f / l_r[r];
        int row = q0 + wq + lg * 4 + r;
        float* optr = out + (size_t)(b * SEQ + row) * DIM + h * HDIM;
#pragma unroll
        for (int db = 0; db < 8; ++db)
            optr[db * 16 + lr] = oc[db][r] * inv;
    }
}

extern "C" void kernel_launch(void* const* d_in, const int* in_sizes, int n_in,
                              void* d_out, int out_size, void* d_ws, size_t ws_size,
                              hipStream_t stream) {
    const float* x     = (const float*)d_in[0];
    const float* w_qkv = (const float*)d_in[1];
    const float* w_out = (const float*)d_in[2];
    float* out = (float*)d_out;

    float* qkv     = (float*)d_ws;
    float* attn_ws = qkv + (size_t)BATCH * SEQ * 3 * DIM;

    const int Mrows = BATCH * SEQ;

    gemm_nt_split<<<dim3(3 * DIM / 128, Mrows / 128), 256, 0, stream>>>(
        x, w_qkv, qkv, Mrows, 3 * DIM, DIM);

    attn_mfma<<<dim3(SEQ / QB, BATCH * NHEAD), 256, 0, stream>>>(qkv, attn_ws);

    gemm_nt_split<<<dim3(DIM / 128, Mrows / 128), 256, 0, stream>>>(
        attn_ws, w_out, out, Mrows, DIM, DIM);
}